// Round 22
// baseline (82.685 us; speedup 1.0000x reference)
//
#include <hip/hip_runtime.h>
#include <math.h>

// B=256, P=40, S=60, D=64. Round-22: R20's half-width-GEMM body, x moved
// back to REGISTERS with a split live range, LDS = weights only (40 KB).
// Rationale: R21 showed the allocator's working budget for 512-thr WGs is
// ~128 VGPR (it schedules to fit 128 rather than exceed it). R20's x-in-LDS
// fit 112 but cost 100 KB LDS -> 1 WG/CU -> 8 waves/CU. With xf in regs and
// a reload-after-softmax (asm-laundered vs CSE), phase peaks are ~112-128:
//   k-stage xf+qf+kf+acc2 = 112 ; scores qf+kf+pf+acc2 = 112 ; v xf+pf+vf = 112
// -> fits 128. LDS 40 KB -> 4 WGs/CU; VGPR 128 -> 16 waves/CU = 4/SIMD,
// DOUBLE R20's residency. 1280 WGs x 512 thr, one part per wave.
//
// Register-chain trick: MFMA contraction is invariant to permuting the k-dim.
// C/D output holds the row-dim in-lane as {16mt+4g+j}; the next GEMM
// contracting that dim takes both operands by pure register reindexing:
//     frag[nt][ks] = pk16( acc2[2ks][nb], acc2[2ks+1][nb] )
// map pi(ks,i,g)=16*(2ks+(i>>2))+4g+(i&3). W1/W2 pre-permuted to pi-layout.
//
// Layout facts (cdna4 guide, measured m89/m91):
//   C/D: lane holds col=lane&15, rows 16mt+4(lane>>4)+j
//   A/B: row(col)=lane&15, kappa = 32ks+8(lane>>4)+i

typedef _Float16 half8 __attribute__((ext_vector_type(8)));
typedef __fp16 fp16x2 __attribute__((ext_vector_type(2)));
typedef float f4 __attribute__((ext_vector_type(4)));

#define MFMA16(a, b, c) __builtin_amdgcn_mfma_f32_16x16x32_f16((a), (b), (c), 0, 0, 0)

__global__ __launch_bounds__(256) void prep_weights(
    const float* __restrict__ Wq, const float* __restrict__ Wk,
    const float* __restrict__ Wv, const float* __restrict__ W1,
    const float* __restrict__ W2, _Float16* __restrict__ wsH) {
    int idx = blockIdx.x * 256 + threadIdx.x;  // 0..20479
    int m = idx >> 12, r = idx & 4095;
    const float* src = (m == 0) ? Wq : (m == 1) ? Wk : (m == 2) ? Wv
                        : (m == 3) ? W1 : W2;
    float v;
    if (m < 3) {
        v = src[r];  // natural row-major [e][d]
    } else {
        // pi-permuted: position (e, kappa) holds W[e][ d=16*(2ks+(i>>2))+4g+(i&3) ]
        int e = r >> 6, kp = r & 63;
        int ks = kp >> 5, gg = (kp >> 3) & 3, i = kp & 7;
        int d = 16 * (2 * ks + (i >> 2)) + 4 * gg + (i & 3);
        v = src[e * 64 + d];
    }
    wsH[idx] = (_Float16)v;
}

// Packed f32x4 + f32x4 -> half8 via v_cvt_pkrtz_f16_f32 (4 insts).
__device__ __forceinline__ half8 pk8(f4 a, f4 b) {
    union { half8 h; fp16x2 p[4]; } u;
    u.p[0] = __builtin_amdgcn_cvt_pkrtz(a[0], a[1]);
    u.p[1] = __builtin_amdgcn_cvt_pkrtz(a[2], a[3]);
    u.p[2] = __builtin_amdgcn_cvt_pkrtz(b[0], b[1]);
    u.p[3] = __builtin_amdgcn_cvt_pkrtz(b[2], b[3]);
    return u.h;
}

__device__ __forceinline__ void load_x(half8 xf[4][2], const float* __restrict__ xp,
                                       int lo, int g) {
    #pragma unroll
    for (int t = 0; t < 4; ++t) {
        int r = 16 * t + lo;
        #pragma unroll
        for (int ks = 0; ks < 2; ++ks) {
            if (r < 60) {
                const float* p = xp + r * 64 + ks * 32 + g * 8;
                xf[t][ks] = pk8(*(const f4*)p, *(const f4*)(p + 4));
            } else {
                half8 z = {};
                xf[t][ks] = z;
            }
        }
    }
}

// Half-width GEMM into acc2[4][2]: output cols nt in {2h, 2h+1}.
// AEXPR uses (t, ks); BEXPR uses (nt, ks); CEXPR uses (mt, nb, nt).
#define GEMM_H(AEXPR, BEXPR, CEXPR)                                          \
    do {                                                                     \
        _Pragma("unroll")                                                    \
        for (int ks = 0; ks < 2; ++ks) {                                     \
            half8 afr[4], bfr[2];                                            \
            _Pragma("unroll")                                                \
            for (int t = 0; t < 4; ++t) afr[t] = (AEXPR);                    \
            _Pragma("unroll")                                                \
            for (int nb = 0; nb < 2; ++nb) {                                 \
                const int nt = 2 * h + nb; (void)nt;                         \
                bfr[nb] = (BEXPR);                                           \
            }                                                                \
            _Pragma("unroll")                                                \
            for (int mt = 0; mt < 4; ++mt)                                   \
                _Pragma("unroll")                                            \
                for (int nb = 0; nb < 2; ++nb) {                             \
                    const int nt = 2 * h + nb; (void)nt;                     \
                    acc2[mt][nb] = MFMA16(afr[mt], bfr[nb],                  \
                                          ks == 0 ? (CEXPR) : acc2[mt][nb]); \
                }                                                            \
        }                                                                    \
    } while (0)

// acc2 -> pi-layout frags for this half (dst[2h+nb][ks]).
#define MKFR_H(dst, RELU)                                                    \
    do {                                                                     \
        _Pragma("unroll")                                                    \
        for (int nb = 0; nb < 2; ++nb)                                       \
            _Pragma("unroll")                                                \
            for (int ks = 0; ks < 2; ++ks) {                                 \
                f4 a_ = acc2[2 * ks][nb], b_ = acc2[2 * ks + 1][nb];         \
                if (RELU) {                                                  \
                    _Pragma("unroll")                                        \
                    for (int j = 0; j < 4; ++j) {                            \
                        a_[j] = fmaxf(a_[j], 0.f);                           \
                        b_[j] = fmaxf(b_[j], 0.f);                           \
                    }                                                        \
                }                                                            \
                dst[2 * h + nb][ks] = pk8(a_, b_);                           \
            }                                                                \
    } while (0)

// Weight fragment from LDS: matrix widx, row-block RB (row = 16*RB+lo),
// kappa chunk (32ks+8g), XOR-swizzled by (lo&7)<<3 halves.
#define WFRAG(widx, RB) (*(const half8*)&wlds[(widx) * 4096 + (16 * (RB) + lo) * 64 + \
                                              ((32 * ks + 8 * g) ^ ((lo & 7) << 3))])

__global__ __launch_bounds__(512, 1) void fused_f16(
    const float* __restrict__ x, const _Float16* __restrict__ wH,
    const float* __restrict__ bq, const float* __restrict__ bk,
    const float* __restrict__ bv, const float* __restrict__ b1,
    const float* __restrict__ b2, const float* __restrict__ W3,
    const float* __restrict__ b3, float* __restrict__ out) {
    __shared__ __align__(16) _Float16 wlds[20480];  // weights only: 40 KB

    const int tid = threadIdx.x;
    const int l = tid & 63;           // lane
    const int w = tid >> 6;           // wave 0..7 (one part each)
    const int lo = l & 15, g = l >> 4;

    // ---- cooperative weight load global->LDS with write-side swizzle.
    #pragma unroll
    for (int rep = 0; rep < 5; ++rep) {
        int chunk = rep * 512 + tid;          // 0..2559
        int widx = chunk >> 9;
        int rem = chunk & 511;
        int row = rem >> 3, c = rem & 7;
        *(half8*)&wlds[widx * 4096 + row * 64 + ((c * 8) ^ ((row & 7) << 3))] =
            *(const half8*)&wH[widx * 4096 + row * 64 + c * 8];
    }
    __syncthreads();  // weights visible to all; waves independent afterwards

    const int part = blockIdx.x * 8 + w;   // one part per wave
    const float* __restrict__ xp = x + (size_t)part * (60 * 64);

    const f4 zc = {0.f, 0.f, 0.f, 0.f};
    f4 acc2[4][2];
    f4 brow[4];
    half8 xf[4][2], qf[4][2], kf[4][2], vf[4][2], pf[4][2], wtf[4][2],
          h1f[4][2];

    load_x(xf, xp, lo, g);

    // ---- qT = Wq * xT + bq
    #pragma unroll
    for (int mt = 0; mt < 4; ++mt) brow[mt] = *(const f4*)&bq[16 * mt + 4 * g];
    #pragma unroll
    for (int h = 0; h < 2; ++h) {
        GEMM_H(WFRAG(0, t), xf[nt][ks], brow[mt]);
        MKFR_H(qf, false);
    }

    // ---- kT = Wk * xT + bk   (peak: xf+qf+kf+acc2 ~ 112)
    #pragma unroll
    for (int mt = 0; mt < 4; ++mt) brow[mt] = *(const f4*)&bk[16 * mt + 4 * g];
    #pragma unroll
    for (int h = 0; h < 2; ++h) {
        GEMM_H(WFRAG(1, t), xf[nt][ks], brow[mt]);
        MKFR_H(kf, false);
    }
    // xf dead here (reloaded after softmax).

    // ---- scoresT + softmax + P, per half (A = kf regs, B = qf half)
    #pragma unroll
    for (int h = 0; h < 2; ++h) {
        GEMM_H(kf[t][ks], qf[nt][ks], zc);
        #pragma unroll
        for (int nb = 0; nb < 2; ++nb) {
            float sum = 0.f;
            #pragma unroll
            for (int mt = 0; mt < 4; ++mt)
                #pragma unroll
                for (int j = 0; j < 4; ++j) {
                    float e = (mt == 3 && g == 3)
                                  ? 0.f
                                  : exp2f(acc2[mt][nb][j] * 0.1803368801111137f);
                    acc2[mt][nb][j] = e;
                    sum += e;
                }
            sum += __shfl_xor(sum, 16);
            sum += __shfl_xor(sum, 32);
            float inv = 1.f / sum;
            #pragma unroll
            for (int mt = 0; mt < 4; ++mt)
                #pragma unroll
                for (int j = 0; j < 4; ++j) acc2[mt][nb][j] *= inv;
        }
        MKFR_H(pf, false);
    }
    // qf, kf dead here.

    // ---- RELOAD x (live-range split; launder so CSE can't merge with the
    // first load and stretch xf across the whole kernel). L2-hot.
    {
        const float* xp2 = xp;
        asm volatile("" : "+v"(xp2));
        load_x(xf, xp2, lo, g);
    }

    // ---- v = x * WvT + bv (col-splat C-in)  (peak: xf+pf+vf+acc2 ~ 112)
    #pragma unroll
    for (int h = 0; h < 2; ++h) {
        float bc[2];
        #pragma unroll
        for (int nb = 0; nb < 2; ++nb) bc[nb] = bv[16 * (2 * h + nb) + lo];
        GEMM_H(xf[t][ks], WFRAG(2, nt),
               ((f4){bc[nb], bc[nb], bc[nb], bc[nb]}));
        MKFR_H(vf, false);
    }

    // ---- weightedT = vT * P, per half (A = vf regs, B = pf half)
    #pragma unroll
    for (int h = 0; h < 2; ++h) {
        GEMM_H(vf[t][ks], pf[nt][ks], zc);
        MKFR_H(wtf, false);
    }
    // vf, pf dead here.

    // ---- h1T = relu(W1 * weightedT + b1)   (W1 pi-permuted)
    #pragma unroll
    for (int mt = 0; mt < 4; ++mt) brow[mt] = *(const f4*)&b1[16 * mt + 4 * g];
    #pragma unroll
    for (int h = 0; h < 2; ++h) {
        GEMM_H(WFRAG(3, t), wtf[nt][ks], brow[mt]);
        MKFR_H(h1f, true);
    }

    // ---- h2T = relu(W2 * h1T + b2), head folded per half on f32 acc
    #pragma unroll
    for (int mt = 0; mt < 4; ++mt) brow[mt] = *(const f4*)&b2[16 * mt + 4 * g];
    f4 w3r[4];
    #pragma unroll
    for (int mt = 0; mt < 4; ++mt) w3r[mt] = *(const f4*)&W3[16 * mt + 4 * g];
    float b3v = b3[0];
    #pragma unroll
    for (int h = 0; h < 2; ++h) {
        GEMM_H(WFRAG(4, t), h1f[nt][ks], brow[mt]);
        #pragma unroll
        for (int nb = 0; nb < 2; ++nb) {
            float sres = 0.f;
            #pragma unroll
            for (int mt = 0; mt < 4; ++mt)
                #pragma unroll
                for (int j = 0; j < 4; ++j)
                    sres += fmaxf(acc2[mt][nb][j], 0.f) * w3r[mt][j];
            sres += __shfl_xor(sres, 16);
            sres += __shfl_xor(sres, 32);
            if (g == 0) {
                int s = 16 * (2 * h + nb) + lo;
                if (s < 60) out[(size_t)part * 60 + s] = sres + b3v;
            }
        }
    }
}

extern "C" void kernel_launch(void* const* d_in, const int* in_sizes, int n_in,
                              void* d_out, int out_size, void* d_ws, size_t ws_size,
                              hipStream_t stream) {
    const float* x  = (const float*)d_in[0];
    const float* Wq = (const float*)d_in[1];
    const float* bq = (const float*)d_in[2];
    const float* Wk = (const float*)d_in[3];
    const float* bk = (const float*)d_in[4];
    const float* Wv = (const float*)d_in[5];
    const float* bv = (const float*)d_in[6];
    const float* W1 = (const float*)d_in[7];
    const float* b1 = (const float*)d_in[8];
    const float* W2 = (const float*)d_in[9];
    const float* b2 = (const float*)d_in[10];
    const float* W3 = (const float*)d_in[11];
    const float* b3 = (const float*)d_in[12];
    _Float16* wsH = (_Float16*)d_ws;  // 5 * 4096 halves = 40 KB

    prep_weights<<<80, 256, 0, stream>>>(Wq, Wk, Wv, W1, W2, wsH);
    // 1280 WGs x 512 thr = 8 waves/WG, one part per wave; LDS = 40 KB weights
    // only -> 4 WGs/CU; target VGPR ~128 -> 16 waves/CU = 4 waves/SIMD.
    fused_f16<<<1280, 512, 0, stream>>>(x, wsH, bq, bk, bv, b1, b2, W3, b3,
                                        (float*)d_out);
}